// Round 3
// baseline (1153.947 us; speedup 1.0000x reference)
//
#include <hip/hip_runtime.h>

#define N_NODES 100000
#define HID 64
#define N_EDGES 1600000
#define SCAN_B 1024
#define N_SCAN_BLOCKS ((N_NODES + SCAN_B - 1) / SCAN_B)   // 98

// ---------------------------------------------------------------- gather
__global__ void gather_kernel(const float* __restrict__ emb,
                              const int* __restrict__ nid,
                              float* __restrict__ x) {
    int i = blockIdx.x * blockDim.x + threadIdx.x;
    const int total = N_NODES * (HID / 4);
    if (i >= total) return;
    int row = i >> 4;
    int c   = i & 15;
    int s   = nid[row];
    reinterpret_cast<float4*>(x)[row * 16 + c] =
        reinterpret_cast<const float4*>(emb)[s * 16 + c];
}

// ---------------------------------------------------------------- degree (int)
__global__ void deg_kernel(const int* __restrict__ dst,
                           int* __restrict__ degi) {
    int e = blockIdx.x * blockDim.x + threadIdx.x;
    if (e < N_EDGES) atomicAdd(&degi[dst[e]], 1);
}

// ---------------------------------------------------------------- scan phase A
__global__ void scan_block(const int* __restrict__ degi,
                           int* __restrict__ row_start,
                           int* __restrict__ bsums) {
    __shared__ int s[SCAN_B];
    int gid = blockIdx.x * SCAN_B + threadIdx.x;
    int v = (gid < N_NODES) ? degi[gid] : 0;
    s[threadIdx.x] = v;
    __syncthreads();
    for (int off = 1; off < SCAN_B; off <<= 1) {
        int t = (threadIdx.x >= off) ? s[threadIdx.x - off] : 0;
        __syncthreads();
        s[threadIdx.x] += t;
        __syncthreads();
    }
    if (gid < N_NODES) row_start[gid + 1] = s[threadIdx.x];
    if (threadIdx.x == SCAN_B - 1) bsums[blockIdx.x] = s[SCAN_B - 1];
}

// ---------------------------------------------------------------- scan phase B
__global__ void scan_bsums(int* __restrict__ bsums) {
    __shared__ int s[128];
    int v = (threadIdx.x < N_SCAN_BLOCKS) ? bsums[threadIdx.x] : 0;
    s[threadIdx.x] = v;
    __syncthreads();
    for (int off = 1; off < 128; off <<= 1) {
        int t = (threadIdx.x >= off) ? s[threadIdx.x - off] : 0;
        __syncthreads();
        s[threadIdx.x] += t;
        __syncthreads();
    }
    if (threadIdx.x < N_SCAN_BLOCKS) bsums[threadIdx.x] = s[threadIdx.x] - v; // exclusive
}

// ---------------------------------------------------------------- scan phase C
__global__ void scan_add(int* __restrict__ row_start,
                         const int* __restrict__ bsums) {
    int gid = blockIdx.x * SCAN_B + threadIdx.x;
    if (gid < N_NODES) row_start[gid + 1] += bsums[blockIdx.x];
    if (gid == 0) row_start[0] = 0;
}

// ---------------------------------------------------------------- CSR fill
__global__ void fill_adj(const int* __restrict__ src,
                         const int* __restrict__ dst,
                         const int* __restrict__ row_start,
                         int* __restrict__ cursor,
                         int* __restrict__ adj) {
    int e = blockIdx.x * blockDim.x + threadIdx.x;
    if (e >= N_EDGES) return;
    int d = dst[e];
    int pos = atomicAdd(&cursor[d], 1);
    adj[row_start[d] + pos] = src[e];
}

// ---------------------------------------------------------------- fused SAGE layer
// block=512 (8 waves): LDS 33KB x 4 blocks = 132KB <= 160KB -> 32 waves/CU (100%).
// __launch_bounds__(512, 8) pins VGPR <= 64 so occupancy is wave-capped, not VGPR-capped.
__global__ void __launch_bounds__(512, 8)
sage_layer(const int* __restrict__ row_start,
           const int* __restrict__ adj,
           const int* __restrict__ degi,
           const float* __restrict__ x,
           const float* __restrict__ Wl,
           const float* __restrict__ Wr,
           const float* __restrict__ b,
           float* __restrict__ out,
           int relu) {
    __shared__ float sWl[HID * HID];
    __shared__ float sWr[HID * HID];
    __shared__ float sb[HID];
    for (int idx = threadIdx.x; idx < HID * HID; idx += blockDim.x) {
        int k = idx >> 6, o = idx & 63;
        sWl[idx] = Wl[o * HID + k];   // transposed: lane o reads k*64+o, 2-way (free)
        sWr[idx] = Wr[o * HID + k];
    }
    if (threadIdx.x < HID) sb[threadIdx.x] = b[threadIdx.x];
    __syncthreads();

    int lane = threadIdx.x & 63;
    int wpb = blockDim.x >> 6;
    int wid = blockIdx.x * wpb + (threadIdx.x >> 6);
    int stride = gridDim.x * wpb;
    for (int row = wid; row < N_NODES; row += stride) {
        int beg = row_start[row], end = row_start[row + 1];
        float acc = 0.0f;
        int j = beg;
        for (; j + 3 < end; j += 4) {          // 4 gathers in flight
            int s0 = adj[j], s1 = adj[j + 1], s2 = adj[j + 2], s3 = adj[j + 3];
            float v0 = x[(size_t)s0 * HID + lane];
            float v1 = x[(size_t)s1 * HID + lane];
            float v2 = x[(size_t)s2 * HID + lane];
            float v3 = x[(size_t)s3 * HID + lane];
            acc += v0; acc += v1; acc += v2; acc += v3;
        }
        for (; j < end; ++j) acc += x[(size_t)adj[j] * HID + lane];

        float d  = (float)degi[row];
        float a  = acc / fmaxf(d, 1.0f);
        float xv = x[(size_t)row * HID + lane];
        float o  = sb[lane];
        #pragma unroll
        for (int k = 0; k < HID; ++k) {
            o += __shfl(a, k)  * sWl[k * HID + lane];
            o += __shfl(xv, k) * sWr[k * HID + lane];
        }
        if (relu) o = fmaxf(o, 0.0f);
        out[(size_t)row * HID + lane] = o;
    }
}

// ---------------------------------------------------------------- edge dot
__global__ void edge_dot_kernel(const int* __restrict__ src,
                                const int* __restrict__ dst,
                                const float* __restrict__ h,
                                float* __restrict__ out) {
    int t = blockIdx.x * blockDim.x + threadIdx.x;
    int e = t >> 4;
    int c = t & 15;
    if (e >= N_EDGES) return;
    int a = src[e], bn = dst[e];
    float4 va = reinterpret_cast<const float4*>(h)[a * 16 + c];
    float4 vb = reinterpret_cast<const float4*>(h)[bn * 16 + c];
    float p = va.x * vb.x + va.y * vb.y + va.z * vb.z + va.w * vb.w;
    p += __shfl_xor(p, 1);
    p += __shfl_xor(p, 2);
    p += __shfl_xor(p, 4);
    p += __shfl_xor(p, 8);
    if (c == 0) out[e] = p;
}

extern "C" void kernel_launch(void* const* d_in, const int* in_sizes, int n_in,
                              void* d_out, int out_size, void* d_ws, size_t ws_size,
                              hipStream_t stream) {
    const float* emb = (const float*)d_in[0];
    const float* Wl1 = (const float*)d_in[1];
    const float* Wr1 = (const float*)d_in[2];
    const float* b1  = (const float*)d_in[3];
    const float* Wl2 = (const float*)d_in[4];
    const float* Wr2 = (const float*)d_in[5];
    const float* b2  = (const float*)d_in[6];
    const int*   nid = (const int*)d_in[7];
    const int*   ei  = (const int*)d_in[8];
    const int* esrc = ei;
    const int* edst = ei + N_EDGES;
    float* out = (float*)d_out;

    const size_t NH = (size_t)N_NODES * HID;
    float* ws = (float*)d_ws;
    float* x  = ws;            // [N,64] (reused as h2)
    float* h1 = ws + NH;       // [N,64]
    int* ib        = (int*)(ws + 2 * NH);
    int* degi      = ib;                          // [N]
    int* cursor    = ib + N_NODES;                // [N]
    int* row_start = ib + 2 * N_NODES;            // [N+1]
    int* adj       = ib + 3 * N_NODES + 64;       // [E]
    int* bsums     = adj + N_EDGES + 64;          // [128]

    hipMemsetAsync(degi, 0, 2 * (size_t)N_NODES * sizeof(int), stream);

    gather_kernel<<<(N_NODES * 16 + 255) / 256, 256, 0, stream>>>(emb, nid, x);

    // ---- CSR build (shared by both layers)
    deg_kernel<<<(N_EDGES + 255) / 256, 256, 0, stream>>>(edst, degi);
    scan_block<<<N_SCAN_BLOCKS, SCAN_B, 0, stream>>>(degi, row_start, bsums);
    scan_bsums<<<1, 128, 0, stream>>>(bsums);
    scan_add<<<N_SCAN_BLOCKS, SCAN_B, 0, stream>>>(row_start, bsums);
    fill_adj<<<(N_EDGES + 255) / 256, 256, 0, stream>>>(esrc, edst, row_start, cursor, adj);

    // ---- layer 1 (fused aggregate + combine + relu); 1024 blocks = 4 resident/CU
    sage_layer<<<1024, 512, 0, stream>>>(row_start, adj, degi, x, Wl1, Wr1, b1, h1, 1);
    // ---- layer 2
    sage_layer<<<1024, 512, 0, stream>>>(row_start, adj, degi, h1, Wl2, Wr2, b2, x /*h2*/, 0);

    // ---- edge classifier
    edge_dot_kernel<<<((size_t)N_EDGES * 16 + 255) / 256, 256, 0, stream>>>(esrc, edst, x, out);
}

// Round 4
// 925.855 us; speedup vs baseline: 1.2464x; 1.2464x over previous
//
#include <hip/hip_runtime.h>

#define N_NODES 100000
#define HID 64
#define N_EDGES 1600000
#define SCAN_B 1024
#define N_SCAN_BLOCKS ((N_NODES + SCAN_B - 1) / SCAN_B)   // 98

// ---- bf16 helpers (manual, RNE) ------------------------------------------
__device__ __forceinline__ unsigned short f2bf(float f) {
    unsigned u = __float_as_uint(f);
    u = (u + 0x7FFFu + ((u >> 16) & 1u)) >> 16;
    return (unsigned short)u;
}
__device__ __forceinline__ float bf2f(unsigned short h) {
    return __uint_as_float(((unsigned)h) << 16);
}
__device__ __forceinline__ float bflo(unsigned w) { return __uint_as_float(w << 16); }
__device__ __forceinline__ float bfhi(unsigned w) { return __uint_as_float(w & 0xFFFF0000u); }

// ---------------------------------------------------------------- gather->bf16
// xh[i][:] = bf16(emb[node_id[i]][:]) ; one float4 -> packed uint2 per thread
__global__ void gather_bf16_kernel(const float* __restrict__ emb,
                                   const int* __restrict__ nid,
                                   unsigned short* __restrict__ xh) {
    int i = blockIdx.x * blockDim.x + threadIdx.x;
    const int total = N_NODES * (HID / 4);
    if (i >= total) return;
    int row = i >> 4;
    int c   = i & 15;
    int s   = nid[row];
    float4 v = reinterpret_cast<const float4*>(emb)[(size_t)s * 16 + c];
    uint2 p;
    p.x = (unsigned)f2bf(v.x) | ((unsigned)f2bf(v.y) << 16);
    p.y = (unsigned)f2bf(v.z) | ((unsigned)f2bf(v.w) << 16);
    reinterpret_cast<uint2*>(xh)[(size_t)row * 16 + c] = p;
}

// ---------------------------------------------------------------- degree (int)
__global__ void deg_kernel(const int* __restrict__ dst,
                           int* __restrict__ degi) {
    int e = blockIdx.x * blockDim.x + threadIdx.x;
    if (e < N_EDGES) atomicAdd(&degi[dst[e]], 1);
}

// ---------------------------------------------------------------- scan phase A
__global__ void scan_block(const int* __restrict__ degi,
                           int* __restrict__ row_start,
                           int* __restrict__ bsums) {
    __shared__ int s[SCAN_B];
    int gid = blockIdx.x * SCAN_B + threadIdx.x;
    int v = (gid < N_NODES) ? degi[gid] : 0;
    s[threadIdx.x] = v;
    __syncthreads();
    for (int off = 1; off < SCAN_B; off <<= 1) {
        int t = (threadIdx.x >= off) ? s[threadIdx.x - off] : 0;
        __syncthreads();
        s[threadIdx.x] += t;
        __syncthreads();
    }
    if (gid < N_NODES) row_start[gid + 1] = s[threadIdx.x];
    if (threadIdx.x == SCAN_B - 1) bsums[blockIdx.x] = s[SCAN_B - 1];
}

// ---------------------------------------------------------------- scan phase B
__global__ void scan_bsums(int* __restrict__ bsums) {
    __shared__ int s[128];
    int v = (threadIdx.x < N_SCAN_BLOCKS) ? bsums[threadIdx.x] : 0;
    s[threadIdx.x] = v;
    __syncthreads();
    for (int off = 1; off < 128; off <<= 1) {
        int t = (threadIdx.x >= off) ? s[threadIdx.x - off] : 0;
        __syncthreads();
        s[threadIdx.x] += t;
        __syncthreads();
    }
    if (threadIdx.x < N_SCAN_BLOCKS) bsums[threadIdx.x] = s[threadIdx.x] - v; // exclusive
}

// ---------------------------------------------------------------- scan phase C
__global__ void scan_add(int* __restrict__ row_start,
                         const int* __restrict__ bsums) {
    int gid = blockIdx.x * SCAN_B + threadIdx.x;
    if (gid < N_NODES) row_start[gid + 1] += bsums[blockIdx.x];
    if (gid == 0) row_start[0] = 0;
}

// ---------------------------------------------------------------- CSR fill
__global__ void fill_adj(const int* __restrict__ src,
                         const int* __restrict__ dst,
                         const int* __restrict__ row_start,
                         int* __restrict__ cursor,
                         int* __restrict__ adj) {
    int e = blockIdx.x * blockDim.x + threadIdx.x;
    if (e >= N_EDGES) return;
    int d = dst[e];
    int pos = atomicAdd(&cursor[d], 1);
    adj[row_start[d] + pos] = src[e];
}

// ---------------------------------------------------------------- fused SAGE layer
// R2-proven shape: 256 threads, 1024 blocks. Gathers read bf16 rows (128 B),
// fp32 accumulate; self term (Wr path) reads fp32 (exact); writes fp32 (opt) + bf16.
__global__ void sage_layer(const int* __restrict__ row_start,
                           const int* __restrict__ adj,
                           const float* __restrict__ selfmat,   // fp32 matrix for self term
                           const int* __restrict__ self_idx,    // nid for layer1, null = identity
                           const unsigned short* __restrict__ xh, // bf16 gather source
                           const float* __restrict__ Wl,
                           const float* __restrict__ Wr,
                           const float* __restrict__ b,
                           float* __restrict__ out_f32,         // nullable
                           unsigned short* __restrict__ out_bf16,
                           int relu) {
    __shared__ float sWl[HID * HID];
    __shared__ float sWr[HID * HID];
    __shared__ float sb[HID];
    for (int idx = threadIdx.x; idx < HID * HID; idx += blockDim.x) {
        int k = idx >> 6, o = idx & 63;
        sWl[idx] = Wl[o * HID + k];   // transposed: lane o reads k*64+o, 2-way (free)
        sWr[idx] = Wr[o * HID + k];
    }
    if (threadIdx.x < HID) sb[threadIdx.x] = b[threadIdx.x];
    __syncthreads();

    int lane = threadIdx.x & 63;
    int wpb = blockDim.x >> 6;
    int wid = blockIdx.x * wpb + (threadIdx.x >> 6);
    int stride = gridDim.x * wpb;
    for (int row = wid; row < N_NODES; row += stride) {
        int beg = row_start[row], end = row_start[row + 1];
        float acc = 0.0f;
        int j = beg;
        for (; j + 3 < end; j += 4) {          // 4 gathers in flight
            int s0 = adj[j], s1 = adj[j + 1], s2 = adj[j + 2], s3 = adj[j + 3];
            unsigned short v0 = xh[(size_t)s0 * HID + lane];
            unsigned short v1 = xh[(size_t)s1 * HID + lane];
            unsigned short v2 = xh[(size_t)s2 * HID + lane];
            unsigned short v3 = xh[(size_t)s3 * HID + lane];
            acc += bf2f(v0); acc += bf2f(v1); acc += bf2f(v2); acc += bf2f(v3);
        }
        for (; j < end; ++j) acc += bf2f(xh[(size_t)adj[j] * HID + lane]);

        int srow = self_idx ? self_idx[row] : row;
        float xv = selfmat[(size_t)srow * HID + lane];
        float d  = (float)(end - beg);
        float a  = acc / fmaxf(d, 1.0f);
        float o  = sb[lane];
        #pragma unroll
        for (int k = 0; k < HID; ++k) {
            o += __shfl(a, k)  * sWl[k * HID + lane];
            o += __shfl(xv, k) * sWr[k * HID + lane];
        }
        if (relu) o = fmaxf(o, 0.0f);
        if (out_f32) out_f32[(size_t)row * HID + lane] = o;
        out_bf16[(size_t)row * HID + lane] = f2bf(o);
    }
}

// ---------------------------------------------------------------- edge dot (bf16)
// 16 lanes per edge; each lane loads uint2 = 4 bf16 from each endpoint row (128 B/row).
__global__ void edge_dot_kernel(const int* __restrict__ src,
                                const int* __restrict__ dst,
                                const unsigned short* __restrict__ h,
                                float* __restrict__ out) {
    int t = blockIdx.x * blockDim.x + threadIdx.x;
    int e = t >> 4;
    int c = t & 15;
    if (e >= N_EDGES) return;
    int a = src[e], bn = dst[e];
    uint2 va = reinterpret_cast<const uint2*>(h)[(size_t)a  * 16 + c];
    uint2 vb = reinterpret_cast<const uint2*>(h)[(size_t)bn * 16 + c];
    float p = bflo(va.x) * bflo(vb.x) + bfhi(va.x) * bfhi(vb.x)
            + bflo(va.y) * bflo(vb.y) + bfhi(va.y) * bfhi(vb.y);
    p += __shfl_xor(p, 1);
    p += __shfl_xor(p, 2);
    p += __shfl_xor(p, 4);
    p += __shfl_xor(p, 8);
    if (c == 0) out[e] = p;
}

extern "C" void kernel_launch(void* const* d_in, const int* in_sizes, int n_in,
                              void* d_out, int out_size, void* d_ws, size_t ws_size,
                              hipStream_t stream) {
    const float* emb = (const float*)d_in[0];
    const float* Wl1 = (const float*)d_in[1];
    const float* Wr1 = (const float*)d_in[2];
    const float* b1  = (const float*)d_in[3];
    const float* Wl2 = (const float*)d_in[4];
    const float* Wr2 = (const float*)d_in[5];
    const float* b2  = (const float*)d_in[6];
    const int*   nid = (const int*)d_in[7];
    const int*   ei  = (const int*)d_in[8];
    const int* esrc = ei;
    const int* edst = ei + N_EDGES;
    float* out = (float*)d_out;

    const size_t NH = (size_t)N_NODES * HID;   // 6.4M elements
    float* ws = (float*)d_ws;
    float* h1 = ws;                                       // [N,64] fp32
    unsigned short* xh  = (unsigned short*)(ws + NH);     // [N,64] bf16
    unsigned short* h1h = xh + NH;                        // [N,64] bf16
    unsigned short* h2h = h1h + NH;                       // [N,64] bf16
    int* ib        = (int*)(h2h + NH);
    int* degi      = ib;                          // [N]
    int* cursor    = ib + N_NODES;                // [N]
    int* row_start = ib + 2 * N_NODES;            // [N+1]
    int* adj       = ib + 3 * N_NODES + 64;       // [E]
    int* bsums     = adj + N_EDGES + 64;          // [128]

    hipMemsetAsync(degi, 0, 2 * (size_t)N_NODES * sizeof(int), stream);

    // xh = bf16(emb[node_id])
    gather_bf16_kernel<<<(N_NODES * 16 + 255) / 256, 256, 0, stream>>>(emb, nid, xh);

    // ---- CSR build (shared by both layers)
    deg_kernel<<<(N_EDGES + 255) / 256, 256, 0, stream>>>(edst, degi);
    scan_block<<<N_SCAN_BLOCKS, SCAN_B, 0, stream>>>(degi, row_start, bsums);
    scan_bsums<<<1, 128, 0, stream>>>(bsums);
    scan_add<<<N_SCAN_BLOCKS, SCAN_B, 0, stream>>>(row_start, bsums);
    fill_adj<<<(N_EDGES + 255) / 256, 256, 0, stream>>>(esrc, edst, row_start, cursor, adj);

    // ---- layer 1: self term exact from emb via nid; gathers bf16
    sage_layer<<<1024, 256, 0, stream>>>(row_start, adj, emb, nid, xh,
                                         Wl1, Wr1, b1, h1, h1h, 1);
    // ---- layer 2: self term fp32 from h1; gathers bf16; only bf16 output needed
    sage_layer<<<1024, 256, 0, stream>>>(row_start, adj, h1, nullptr, h1h,
                                         Wl2, Wr2, b2, nullptr, h2h, 0);

    // ---- edge classifier on bf16 features
    edge_dot_kernel<<<((size_t)N_EDGES * 16 + 255) / 256, 256, 0, stream>>>(esrc, edst, h2h, out);
}